// Round 4
// baseline (643.796 us; speedup 1.0000x reference)
//
#include <hip/hip_runtime.h>

#define GCN_N 100000
#define GCN_E 640000
#define GCN_F 128
#define NPB  32          // nodes per tile in fused phase
#define CAP  32          // ELL slots per node (Poisson(6.4): P(deg>32)*N ~ 6e-7)
#define ZROW 100000      // index of the all-zero pad row in xs
#define GRID 1024        // 4 blocks/CU x 256 CU: LDS 80/160KB, VGPR cap 128, 16/32 waves
                         // -> co-residency guaranteed with ~2x margin (software grid barrier is safe)
#define TTOT (GRID * 256)

typedef __attribute__((ext_vector_type(8))) short bf16x8;
typedef __attribute__((ext_vector_type(4))) float f32x4;
typedef __attribute__((ext_vector_type(8))) unsigned short ushort8;

// ---------------------------------------------------------------- bf16 helpers
__device__ inline unsigned short f2bf(float f) {
    unsigned u = __float_as_uint(f);
    return (unsigned short)((u + 0x7fff + ((u >> 16) & 1)) >> 16);
}
__device__ inline float bflo(unsigned u) { return __uint_as_float(u << 16); }
__device__ inline float bfhi(unsigned u) { return __uint_as_float(u & 0xffff0000u); }

// ---------------------------------------------------------------- software grid barrier
// bar[0] = arrive counter, bar[1] = generation. Device-scope atomics + fences
// (same construction as the cg grid.sync device-library impl). bar is
// memset to 0 before each launch -> deterministic under graph replay.
__device__ inline void grid_barrier(int* bar) {
    __syncthreads();
    if (threadIdx.x == 0) {
        __threadfence();   // release: make this block's prior writes visible
        int g = __hip_atomic_load(&bar[1], __ATOMIC_RELAXED, __HIP_MEMORY_SCOPE_AGENT);
        int a = __hip_atomic_fetch_add(&bar[0], 1, __ATOMIC_ACQ_REL, __HIP_MEMORY_SCOPE_AGENT);
        if (a == GRID - 1) {
            __hip_atomic_store(&bar[0], 0, __ATOMIC_RELAXED, __HIP_MEMORY_SCOPE_AGENT);
            __hip_atomic_fetch_add(&bar[1], 1, __ATOMIC_RELEASE, __HIP_MEMORY_SCOPE_AGENT);
        } else {
            while (__hip_atomic_load(&bar[1], __ATOMIC_ACQUIRE, __HIP_MEMORY_SCOPE_AGENT) == g) {
                __builtin_amdgcn_s_sleep(2);
            }
        }
        __threadfence();   // acquire: invalidate stale cached lines
    }
    __syncthreads();
}

// ---------------------------------------------------------------- single persistent kernel, 4 phases
// P0: zero cnt, ZROW-init ell, zero xs pad row, build W MFMA fragments (bf16 hi/lo)
// P1: ELL fill via atomics (1 edge / grid-stride iter)
// P2: xs = bf16(dinv * x)
// P3: per-32-node tile: ELL gather (wave-uniform) + split-precision MFMA GEMM + bias
__global__ __launch_bounds__(256, 4) void gcn_all(
        const float* __restrict__ x, const int* __restrict__ rows,
        const int* __restrict__ cols, const float* __restrict__ W,
        const float* __restrict__ b, int* __restrict__ cnt,
        int* __restrict__ ell, ushort* __restrict__ xs,
        ushort* __restrict__ wfh, ushort* __restrict__ wfl,
        float* __restrict__ out, int* __restrict__ bar) {
    __shared__ ushort Ah[NPB * GCN_F];     // 8 KB, XOR-swizzled bf16 hi
    __shared__ ushort Al[NPB * GCN_F];     // 8 KB, bf16 lo (residual)
    __shared__ int    sell[NPB * CAP];     // 4 KB   (total 20480 B)

    int t   = threadIdx.x;
    int tid = blockIdx.x * 256 + t;

    // ---------------- P0: init + W fragments
    {
        int4 z4 = make_int4(0, 0, 0, 0);
        for (int i = tid; i < GCN_N / 4; i += TTOT) ((int4*)cnt)[i] = z4;
        int4 zr = make_int4(ZROW, ZROW, ZROW, ZROW);
        for (int i = tid; i < GCN_N * CAP / 4; i += TTOT) ((int4*)ell)[i] = zr;
        if (tid < 32) ((ushort4*)xs)[(size_t)ZROW * 32 + tid] = make_ushort4(0, 0, 0, 0);
        if (tid >= 2048 && tid < 4096) {
            // W fragment layout: [kt(4)][nt(8)][lane(64)][8 bf16]
            // lane l of frag (kt,nt) holds W[kt*32 + (l>>4)*8 + j][nt*16 + (l&15)], j=0..7
            int pi   = (tid - 2048) >> 6;      // 0..31 = (kt,nt)
            int lane = tid & 63;
            int kt = pi >> 3, nt = pi & 7;
            int kr   = kt * 32 + ((lane >> 4) * 8);
            int ncol = nt * 16 + (lane & 15);
            ushort8 hv, lv;
#pragma unroll
            for (int j = 0; j < 8; ++j) {
                float w = W[(size_t)(kr + j) * GCN_F + ncol];
                unsigned short h = f2bf(w);
                hv[j] = h;
                lv[j] = f2bf(w - bflo((unsigned)h));
            }
            size_t fo = (size_t)(kt * 8 + nt) * 64 + lane;
            ((ushort8*)wfh)[fo] = hv;
            ((ushort8*)wfl)[fo] = lv;
        }
    }
    grid_barrier(bar);

    // ---------------- P1: ELL fill (independent atomic chains)
    for (int e = tid; e < GCN_E; e += TTOT) {
        int c = cols[e], r = rows[e];
        int k = atomicAdd(&cnt[c], 1);
        if (k < CAP) ell[(size_t)c * CAP + k] = r;
    }
    grid_barrier(bar);

    // ---------------- P2: xs = bf16(dinv * x)
    for (int i = tid; i < GCN_N * 32; i += TTOT) {   // float4 / ushort4 index
        int node = i >> 5;
        float di = rsqrtf(2.0f + (float)cnt[node]);  // improved: self-loop weight 2.0
        float4 v = ((const float4*)x)[i];
        ushort4 o;
        o.x = f2bf(di * v.x); o.y = f2bf(di * v.y);
        o.z = f2bf(di * v.z); o.w = f2bf(di * v.w);
        ((ushort4*)xs)[i] = o;
    }
    grid_barrier(bar);

    // ---------------- P3: fused gather + MFMA GEMM, grid-stride over tiles
    int lane  = t & 63;
    int wv    = t >> 6;
    int lrow  = lane & 15;
    int lhalf = lane >> 4;
    const unsigned* xs2 = (const unsigned*)xs;       // 64 x 4B per row
    const bf16x8* whp = (const bf16x8*)wfh;
    const bf16x8* wlp = (const bf16x8*)wfl;
    int nt0 = wv * 2;

    for (int tile = blockIdx.x; tile < GCN_N / NPB; tile += GRID) {
        int row0 = tile * NPB;

        // stage ELL slice (2048 ints, already ZROW-padded): 2 x int4 per thread
        const int4* esrc = (const int4*)(ell + (size_t)row0 * CAP);
        ((int4*)sell)[t]       = esrc[t];
        ((int4*)sell)[t + 256] = esrc[t + 256];
        __syncthreads();

        // ---- gather-accumulate, wave-uniform, 8-deep
        for (int q = 0; q < 8; ++q) {
            int rr = wv * 8 + q;
            int c  = row0 + rr;
            int degc = __builtin_amdgcn_readfirstlane(cnt[c]);
            int deg  = degc > CAP ? CAP : degc;
            const int* sp = &sell[rr * CAP];
            int4 m0 = *(const int4*)sp;              // slots 0..3 (ZROW-padded)
            int4 m1 = *(const int4*)(sp + 4);        // slots 4..7
            unsigned sv = xs2[c * 64 + lane];
            unsigned v0 = xs2[m0.x * 64 + lane];
            unsigned v1 = xs2[m0.y * 64 + lane];
            unsigned v2 = xs2[m0.z * 64 + lane];
            unsigned v3 = xs2[m0.w * 64 + lane];
            unsigned v4 = xs2[m1.x * 64 + lane];
            unsigned v5 = xs2[m1.y * 64 + lane];
            unsigned v6 = xs2[m1.z * 64 + lane];
            unsigned v7 = xs2[m1.w * 64 + lane];
            float ax = 2.0f * bflo(sv);              // self-loop: 2*xs[c]
            float ay = 2.0f * bfhi(sv);
            ax += bflo(v0) + bflo(v1) + bflo(v2) + bflo(v3)
                + bflo(v4) + bflo(v5) + bflo(v6) + bflo(v7);
            ay += bfhi(v0) + bfhi(v1) + bfhi(v2) + bfhi(v3)
                + bfhi(v4) + bfhi(v5) + bfhi(v6) + bfhi(v7);
            if (deg > 8) {                           // wave-uniform branch, ~19% of nodes
                for (int k = 8; k < deg; k += 4) {
                    int4 m = *(const int4*)(sp + k);
                    unsigned u0 = xs2[m.x * 64 + lane];
                    unsigned u1 = xs2[m.y * 64 + lane];
                    unsigned u2 = xs2[m.z * 64 + lane];
                    unsigned u3 = xs2[m.w * 64 + lane];
                    ax += bflo(u0) + bflo(u1) + bflo(u2) + bflo(u3);
                    ay += bfhi(u0) + bfhi(u1) + bfhi(u2) + bfhi(u3);
                }
            }
            float di = rsqrtf(2.0f + (float)degc);
            float axd = di * ax, ayd = di * ay;
            // split-precision bf16: hi + residual lo
            unsigned short hx = f2bf(axd), hy = f2bf(ayd);
            unsigned short lx = f2bf(axd - bflo((unsigned)hx));
            unsigned short ly = f2bf(ayd - bflo((unsigned)hy));
            // XOR swizzle (byte ^= (row&7)<<4) -> conflict-free b128 frag reads
            unsigned off = (unsigned)rr * 256 + (((unsigned)lane * 4) ^ (((unsigned)(rr & 7)) << 4));
            *(unsigned*)((char*)Ah + off) = ((unsigned)hy << 16) | hx;
            *(unsigned*)((char*)Al + off) = ((unsigned)ly << 16) | lx;
        }
        __syncthreads();

        // ---- MFMA GEMM + bias
        // mfma_f32_16x16x32_bf16: A lane l = A[l&15][(l>>4)*8+j]; B lane l = B[(l>>4)*8+j][l&15];
        // D lane l = D[(l>>4)*4+reg][l&15]  (m89-verified layout)
        f32x4 acc[2][2];
#pragma unroll
        for (int m = 0; m < 2; ++m)
#pragma unroll
            for (int n = 0; n < 2; ++n) acc[m][n] = (f32x4)0.f;

#pragma unroll
        for (int kt = 0; kt < 4; ++kt) {
            unsigned kb = ((unsigned)(kt * 64 + lhalf * 16)) ^ (((unsigned)(lane & 7)) << 4);
            unsigned o0 = (unsigned)lrow * 256 + kb;
            bf16x8 ah[2], al[2], wh[2], wl[2];
            ah[0] = *(const bf16x8*)((const char*)Ah + o0);
            ah[1] = *(const bf16x8*)((const char*)Ah + o0 + 4096);
            al[0] = *(const bf16x8*)((const char*)Al + o0);
            al[1] = *(const bf16x8*)((const char*)Al + o0 + 4096);
            wh[0] = whp[(kt * 8 + nt0) * 64 + lane];
            wh[1] = whp[(kt * 8 + nt0 + 1) * 64 + lane];
            wl[0] = wlp[(kt * 8 + nt0) * 64 + lane];
            wl[1] = wlp[(kt * 8 + nt0 + 1) * 64 + lane];
#pragma unroll
            for (int m = 0; m < 2; ++m)
#pragma unroll
                for (int n = 0; n < 2; ++n) {
                    acc[m][n] = __builtin_amdgcn_mfma_f32_16x16x32_bf16(ah[m], wh[n], acc[m][n], 0, 0, 0);
                    acc[m][n] = __builtin_amdgcn_mfma_f32_16x16x32_bf16(ah[m], wl[n], acc[m][n], 0, 0, 0);
                    acc[m][n] = __builtin_amdgcn_mfma_f32_16x16x32_bf16(al[m], wh[n], acc[m][n], 0, 0, 0);
                }
        }

        float b0 = b[wv * 32 + lrow];
        float b1 = b[wv * 32 + 16 + lrow];
#pragma unroll
        for (int m = 0; m < 2; ++m)
#pragma unroll
            for (int n = 0; n < 2; ++n) {
                int col = wv * 32 + n * 16 + lrow;
                float bb = n ? b1 : b0;
#pragma unroll
                for (int j = 0; j < 4; ++j) {
                    int r = row0 + m * 16 + lhalf * 4 + j;
                    out[(size_t)r * GCN_F + col] = acc[m][n][j] + bb;
                }
            }
        // next-iter sell staging is safe: every thread passed the post-gather
        // barrier before re-staging, and MFMA reads only Ah/Al (disjoint from sell).
    }
}

// ---------------------------------------------------------------- launch: memset(8B) + ONE plain dispatch
extern "C" void kernel_launch(void* const* d_in, const int* in_sizes, int n_in,
                              void* d_out, int out_size, void* d_ws, size_t ws_size,
                              hipStream_t stream) {
    const float* x  = (const float*)d_in[0];
    const int*   ei = (const int*)d_in[1];     // [2, E]: rows then cols
    const float* W  = (const float*)d_in[2];
    const float* b  = (const float*)d_in[3];
    float* out = (float*)d_out;

    const int* rows = ei;
    const int* cols = ei + GCN_E;

    // workspace: cnt[N] | bar[2] (in the pad gap) | ell[N*CAP] | xs[(N+1)*128 bf16] | Wfrag hi/lo
    char*   ws  = (char*)d_ws;
    int*    cnt = (int*)(ws + 0);               // 400 KB
    int*    bar = (int*)(ws + 400000);          // 8 B, inside the pre-ell pad gap
    int*    ell = (int*)(ws + 400384);          // 12.8 MB
    ushort* xs  = (ushort*)(ws + 13200384);     // 25.6 MB + pad row
    ushort* wfh = (ushort*)(ws + 38800640);     // 32 KB
    ushort* wfl = (ushort*)(ws + 38833408);     // 32 KB

    hipMemsetAsync(bar, 0, 2 * sizeof(int), stream);
    gcn_all<<<GRID, 256, 0, stream>>>(x, rows, cols, W, b, cnt, ell, xs, wfh, wfl, out, bar);
}

// Round 5
// 178.027 us; speedup vs baseline: 3.6163x; 3.6163x over previous
//
#include <hip/hip_runtime.h>

#define GCN_N 100000
#define GCN_E 640000
#define GCN_F 128
#define NPB  32          // nodes per block in fused kernel
#define CAP  32          // ELL slots per node (Poisson(6.4): P(deg>32)*N ~ 6e-7)
#define ZROW 100000      // index of the all-zero pad row in xs

typedef __attribute__((ext_vector_type(8))) short bf16x8;
typedef __attribute__((ext_vector_type(4))) float f32x4;
typedef __attribute__((ext_vector_type(8))) unsigned short ushort8;

// ---------------------------------------------------------------- bf16 helpers
__device__ inline unsigned short f2bf(float f) {
    unsigned u = __float_as_uint(f);
    return (unsigned short)((u + 0x7fff + ((u >> 16) & 1)) >> 16);
}
__device__ inline float bflo(unsigned u) { return __uint_as_float(u << 16); }
__device__ inline float bfhi(unsigned u) { return __uint_as_float(u & 0xffff0000u); }

// ---------------------------------------------------------------- fill ELL + degree count (one pass)
// 1 edge/thread: independent atomic chains, max latency hiding. E = 2500 * 256.
__global__ void fill_ell(const int* __restrict__ rows, const int* __restrict__ cols,
                         int* __restrict__ cnt, int* __restrict__ ell) {
    int e = blockIdx.x * 256 + threadIdx.x;
    int c = cols[e], r = rows[e];
    int k = atomicAdd(&cnt[c], 1);
    if (k < CAP) ell[(size_t)c * CAP + k] = r;
}

// ---------------------------------------------------------------- xs = bf16(dinv[node] * x), + zero pad row, + W fragments
// Blocks 0..12499 cover x (3.2M float4); block 12500 writes the zero row;
// blocks 12501..12508 build MFMA-fragment-ordered bf16 hi/lo copies of W.
__global__ void scale_conv(const float* __restrict__ x, const int* __restrict__ cnt,
                           ushort* __restrict__ xs, const float* __restrict__ W,
                           ushort* __restrict__ wfh, ushort* __restrict__ wfl) {
    int blk = blockIdx.x;
    int t = threadIdx.x;
    if (blk >= 12501) {
        // W fragment layout: [kt(4)][nt(8)][lane(64)][8 bf16]
        // lane l of frag (kt,nt) holds W[kt*32 + (l>>4)*8 + j][nt*16 + (l&15)], j=0..7
        int p    = blk - 12501;            // 0..7
        int pi   = p * 4 + (t >> 6);       // 0..31 = (kt,nt)
        int lane = t & 63;
        int kt = pi >> 3, nt = pi & 7;
        int kr   = kt * 32 + ((lane >> 4) * 8);
        int ncol = nt * 16 + (lane & 15);
        ushort8 hv, lv;
#pragma unroll
        for (int j = 0; j < 8; ++j) {
            float w = W[(size_t)(kr + j) * GCN_F + ncol];
            unsigned short h = f2bf(w);
            hv[j] = h;
            lv[j] = f2bf(w - bflo((unsigned)h));
        }
        size_t fo = (size_t)(kt * 8 + nt) * 64 + lane;
        ((ushort8*)wfh)[fo] = hv;
        ((ushort8*)wfl)[fo] = lv;
        return;
    }
    if (blk == 12500) {
        if (t < 32) ((ushort4*)xs)[(size_t)ZROW * 32 + t] = make_ushort4(0, 0, 0, 0);
        return;
    }
    int i = blk * 256 + t;                  // float4 / ushort4 index
    int node = i >> 5;
    float di = rsqrtf(2.0f + (float)cnt[node]);   // improved: self-loop weight 2.0
    float4 v = ((const float4*)x)[i];
    ushort4 o;
    o.x = f2bf(di * v.x); o.y = f2bf(di * v.y);
    o.z = f2bf(di * v.z); o.w = f2bf(di * v.w);
    ((ushort4*)xs)[i] = o;
}

// ---------------------------------------------------------------- fused: ELL gather (wave-uniform) + MFMA GEMM + bias
// 256 threads = 4 wave64s; 32 nodes per block. Wave w gathers rows w*8..w*8+7,
// processed in PAIRS with all 34 loads issued before accumulation (deep MLP,
// branch-free main path: 16 unconditional ZROW-padded slots, P(deg>16)~3e-4).
// Phase 2: out[32x128] = As @ W + b via split-precision bf16 MFMA
// (Ahi*Whi + Ahi*Wlo + Alo*Whi ~ fp32 accuracy). Wave w owns cols w*32..w*32+31.
__global__ __launch_bounds__(256) void gcn_fused(
        const ushort* __restrict__ xs, const int* __restrict__ cnt,
        const int* __restrict__ ell, const ushort* __restrict__ wfh,
        const ushort* __restrict__ wfl, const float* __restrict__ b,
        float* __restrict__ out) {
    __shared__ ushort Ah[NPB * GCN_F];     // 8 KB, XOR-swizzled bf16 hi
    __shared__ ushort Al[NPB * GCN_F];     // 8 KB, bf16 lo (residual)
    __shared__ int    sell[NPB * CAP];     // 4 KB
    __shared__ int    scnt[NPB];
    int t = threadIdx.x;
    int row0 = blockIdx.x * NPB;

    if (t < NPB) scnt[t] = cnt[row0 + t];
    __syncthreads();

    // stage ELL slice (contiguous 4KB, coalesced); pad unused slots with ZROW
    for (int i = t; i < NPB * CAP; i += 256) {
        int rr = i >> 5, kk = i & (CAP - 1);
        int v = ell[(size_t)(row0 + rr) * CAP + kk];
        int dg = scnt[rr]; if (dg > CAP) dg = CAP;
        sell[i] = (kk < dg) ? v : ZROW;
    }
    __syncthreads();

    int lane = t & 63;
    int wv   = t >> 6;

    // ---- phase 1: gather-accumulate, wave-uniform, paired nodes / 34-deep loads
    {
        const unsigned* xs2 = (const unsigned*)xs;   // 64 x 4B per row
        for (int qp = 0; qp < 4; ++qp) {
            int r0 = wv * 8 + qp * 2;
            int r1 = r0 + 1;
            const int* sp0 = &sell[r0 * CAP];
            const int* sp1 = &sell[r1 * CAP];
            // ---- issue all loads for node pair (2 x (1 self + 16 slots))
            unsigned s0 = xs2[(row0 + r0) * 64 + lane];
            unsigned v0[16];
#pragma unroll
            for (int k4 = 0; k4 < 4; ++k4) {
                int4 m = *(const int4*)(sp0 + 4 * k4);
                v0[4 * k4 + 0] = xs2[m.x * 64 + lane];
                v0[4 * k4 + 1] = xs2[m.y * 64 + lane];
                v0[4 * k4 + 2] = xs2[m.z * 64 + lane];
                v0[4 * k4 + 3] = xs2[m.w * 64 + lane];
            }
            unsigned s1 = xs2[(row0 + r1) * 64 + lane];
            unsigned v1[16];
#pragma unroll
            for (int k4 = 0; k4 < 4; ++k4) {
                int4 m = *(const int4*)(sp1 + 4 * k4);
                v1[4 * k4 + 0] = xs2[m.x * 64 + lane];
                v1[4 * k4 + 1] = xs2[m.y * 64 + lane];
                v1[4 * k4 + 2] = xs2[m.z * 64 + lane];
                v1[4 * k4 + 3] = xs2[m.w * 64 + lane];
            }
            // ---- accumulate node r0 (earliest loads; r1's stay in flight)
            float ax = 2.0f * bflo(s0), ay = 2.0f * bfhi(s0);
#pragma unroll
            for (int k = 0; k < 16; ++k) { ax += bflo(v0[k]); ay += bfhi(v0[k]); }
            int dc0 = scnt[r0];
            int deg0 = dc0 > CAP ? CAP : dc0;
            if (deg0 > 16) {                         // wave-uniform, ~3e-4 of nodes
                for (int k = 16; k < deg0; k += 4) {
                    int4 m = *(const int4*)(sp0 + k);
                    unsigned u0 = xs2[m.x * 64 + lane];
                    unsigned u1 = xs2[m.y * 64 + lane];
                    unsigned u2 = xs2[m.z * 64 + lane];
                    unsigned u3 = xs2[m.w * 64 + lane];
                    ax += bflo(u0) + bflo(u1) + bflo(u2) + bflo(u3);
                    ay += bfhi(u0) + bfhi(u1) + bfhi(u2) + bfhi(u3);
                }
            }
            {
                float di = rsqrtf(2.0f + (float)dc0);
                float axd = di * ax, ayd = di * ay;
                unsigned short hx = f2bf(axd), hy = f2bf(ayd);
                unsigned short lx = f2bf(axd - bflo((unsigned)hx));
                unsigned short ly = f2bf(ayd - bflo((unsigned)hy));
                // XOR swizzle (byte ^= (row&7)<<4) -> conflict-free b128 frag reads
                unsigned off = (unsigned)r0 * 256 + (((unsigned)lane * 4) ^ (((unsigned)(r0 & 7)) << 4));
                *(unsigned*)((char*)Ah + off) = ((unsigned)hy << 16) | hx;
                *(unsigned*)((char*)Al + off) = ((unsigned)ly << 16) | lx;
            }
            // ---- accumulate node r1
            float bx = 2.0f * bflo(s1), by = 2.0f * bfhi(s1);
#pragma unroll
            for (int k = 0; k < 16; ++k) { bx += bflo(v1[k]); by += bfhi(v1[k]); }
            int dc1 = scnt[r1];
            int deg1 = dc1 > CAP ? CAP : dc1;
            if (deg1 > 16) {
                for (int k = 16; k < deg1; k += 4) {
                    int4 m = *(const int4*)(sp1 + k);
                    unsigned u0 = xs2[m.x * 64 + lane];
                    unsigned u1 = xs2[m.y * 64 + lane];
                    unsigned u2 = xs2[m.z * 64 + lane];
                    unsigned u3 = xs2[m.w * 64 + lane];
                    bx += bflo(u0) + bflo(u1) + bflo(u2) + bflo(u3);
                    by += bfhi(u0) + bfhi(u1) + bfhi(u2) + bfhi(u3);
                }
            }
            {
                float di = rsqrtf(2.0f + (float)dc1);
                float bxd = di * bx, byd = di * by;
                unsigned short hx = f2bf(bxd), hy = f2bf(byd);
                unsigned short lx = f2bf(bxd - bflo((unsigned)hx));
                unsigned short ly = f2bf(byd - bflo((unsigned)hy));
                unsigned off = (unsigned)r1 * 256 + (((unsigned)lane * 4) ^ (((unsigned)(r1 & 7)) << 4));
                *(unsigned*)((char*)Ah + off) = ((unsigned)hy << 16) | hx;
                *(unsigned*)((char*)Al + off) = ((unsigned)ly << 16) | lx;
            }
        }
    }
    __syncthreads();

    // ---- phase 2: MFMA GEMM + bias
    // mfma_f32_16x16x32_bf16: A lane l = A[l&15][(l>>4)*8+j]; B lane l = B[(l>>4)*8+j][l&15];
    // D lane l = D[(l>>4)*4+reg][l&15]  (m89-verified layout)
    int lrow  = lane & 15;
    int lhalf = lane >> 4;
    f32x4 acc[2][2];
#pragma unroll
    for (int m = 0; m < 2; ++m)
#pragma unroll
        for (int n = 0; n < 2; ++n) acc[m][n] = (f32x4)0.f;

    const bf16x8* whp = (const bf16x8*)wfh;
    const bf16x8* wlp = (const bf16x8*)wfl;
    int nt0 = wv * 2;

#pragma unroll
    for (int kt = 0; kt < 4; ++kt) {
        unsigned kb = ((unsigned)(kt * 64 + lhalf * 16)) ^ (((unsigned)(lane & 7)) << 4);
        unsigned o0 = (unsigned)lrow * 256 + kb;
        bf16x8 ah[2], al[2], wh[2], wl[2];
        ah[0] = *(const bf16x8*)((const char*)Ah + o0);
        ah[1] = *(const bf16x8*)((const char*)Ah + o0 + 4096);
        al[0] = *(const bf16x8*)((const char*)Al + o0);
        al[1] = *(const bf16x8*)((const char*)Al + o0 + 4096);
        wh[0] = whp[(kt * 8 + nt0) * 64 + lane];
        wh[1] = whp[(kt * 8 + nt0 + 1) * 64 + lane];
        wl[0] = wlp[(kt * 8 + nt0) * 64 + lane];
        wl[1] = wlp[(kt * 8 + nt0 + 1) * 64 + lane];
#pragma unroll
        for (int m = 0; m < 2; ++m)
#pragma unroll
            for (int n = 0; n < 2; ++n) {
                acc[m][n] = __builtin_amdgcn_mfma_f32_16x16x32_bf16(ah[m], wh[n], acc[m][n], 0, 0, 0);
                acc[m][n] = __builtin_amdgcn_mfma_f32_16x16x32_bf16(ah[m], wl[n], acc[m][n], 0, 0, 0);
                acc[m][n] = __builtin_amdgcn_mfma_f32_16x16x32_bf16(al[m], wh[n], acc[m][n], 0, 0, 0);
            }
    }

    float b0 = b[wv * 32 + lrow];
    float b1 = b[wv * 32 + 16 + lrow];
#pragma unroll
    for (int m = 0; m < 2; ++m)
#pragma unroll
        for (int n = 0; n < 2; ++n) {
            int col = wv * 32 + n * 16 + lrow;
            float bb = n ? b1 : b0;
#pragma unroll
            for (int j = 0; j < 4; ++j) {
                int r = row0 + m * 16 + lhalf * 4 + j;
                out[(size_t)r * GCN_F + col] = acc[m][n][j] + bb;
            }
        }
}

// ---------------------------------------------------------------- launch (4 graph nodes)
extern "C" void kernel_launch(void* const* d_in, const int* in_sizes, int n_in,
                              void* d_out, int out_size, void* d_ws, size_t ws_size,
                              hipStream_t stream) {
    const float* x  = (const float*)d_in[0];
    const int*   ei = (const int*)d_in[1];     // [2, E]: rows then cols
    const float* W  = (const float*)d_in[2];
    const float* b  = (const float*)d_in[3];
    float* out = (float*)d_out;

    const int N = GCN_N, E = GCN_E;
    const int* rows = ei;
    const int* cols = ei + E;

    // workspace: cnt[N] | ell[N*CAP] | xs[(N+1)*128 bf16] | Wfrag hi/lo (32KB each)
    char*   ws  = (char*)d_ws;
    int*    cnt = (int*)(ws + 0);               // 400 KB
    int*    ell = (int*)(ws + 400384);          // 12.8 MB
    ushort* xs  = (ushort*)(ws + 13200384);     // 25.6 MB + pad row
    ushort* wfh = (ushort*)(ws + 38800640);     // 32 KB
    ushort* wfl = (ushort*)(ws + 38833408);     // 32 KB

    hipMemsetAsync(cnt, 0, (size_t)N * sizeof(int), stream);
    fill_ell<<<E / 256, 256, 0, stream>>>(rows, cols, cnt, ell);
    scale_conv<<<12509, 256, 0, stream>>>(x, cnt, xs, W, wfh, wfl);
    gcn_fused<<<N / NPB, 256, 0, stream>>>(xs, cnt, ell, wfh, wfl, b, out);
}